// Round 1
// baseline (813.145 us; speedup 1.0000x reference)
//
#include <hip/hip_runtime.h>
#include <math.h>

#define H 2048
#define G 6144   // 3*H
#define V 50257

// ws layout (float indices):
// [0,     6144)  gi
// [6144, 12288)  gh
// [12288,14336)  h_new
// [14336]        max logit (ordered-uint bits)
// [14337]        sum exp(logit - m)
// [14344, 14344+V) logits
#define WS_GI    0
#define WS_GH    G
#define WS_HNEW  12288
#define WS_MAX   14336
#define WS_SUM   14337
#define WS_LOGIT 14344

__device__ __forceinline__ float waveReduceSum(float v) {
  #pragma unroll
  for (int off = 32; off > 0; off >>= 1) v += __shfl_down(v, off, 64);
  return v;
}

__device__ __forceinline__ unsigned orderedBits(float f) {
  unsigned u = __float_as_uint(f);
  return (u & 0x80000000u) ? ~u : (u | 0x80000000u);
}
__device__ __forceinline__ float orderedToFloat(unsigned m) {
  unsigned u = (m & 0x80000000u) ? (m & 0x7fffffffu) : ~m;
  return __uint_as_float(u);
}

// K1: gi[r] = w_ih[r,:] . relu(emb[token]) + b_ih[r]
//     gh[r] = w_hh[r,:] . h + b_hh[r]
// one wave per row, 4 rows per block
__global__ __launch_bounds__(256) void gates_kernel(
    const int* __restrict__ token, const float* __restrict__ hidden,
    const float* __restrict__ emb, const float* __restrict__ w_ih,
    const float* __restrict__ w_hh, const float* __restrict__ b_ih,
    const float* __restrict__ b_hh, float* __restrict__ ws) {
  const int wave = threadIdx.x >> 6;
  const int lane = threadIdx.x & 63;
  const int row = blockIdx.x * 4 + wave;
  if (row >= G) return;
  const float4* x4 = (const float4*)(emb + (size_t)token[0] * H);
  const float4* h4 = (const float4*)hidden;
  const float4* wi = (const float4*)(w_ih + (size_t)row * H);
  const float4* wh = (const float4*)(w_hh + (size_t)row * H);
  float si = 0.f, sh = 0.f;
  #pragma unroll
  for (int k = 0; k < 8; ++k) {
    const int idx = k * 64 + lane;
    float4 a = wi[idx];
    float4 b = x4[idx];
    si += a.x * fmaxf(b.x, 0.f) + a.y * fmaxf(b.y, 0.f)
        + a.z * fmaxf(b.z, 0.f) + a.w * fmaxf(b.w, 0.f);
    float4 c = wh[idx];
    float4 d = h4[idx];
    sh += c.x * d.x + c.y * d.y + c.z * d.z + c.w * d.w;
  }
  si = waveReduceSum(si);
  sh = waveReduceSum(sh);
  if (lane == 0) {
    ws[WS_GI + row] = si + b_ih[row];
    ws[WS_GH + row] = sh + b_hh[row];
  }
}

// K2: pointwise GRU gate fusion -> h_new; also init softmax reduction cells
__global__ __launch_bounds__(256) void hnew_kernel(
    const float* __restrict__ hidden, float* __restrict__ ws,
    float* __restrict__ out) {
  const int i = blockIdx.x * blockDim.x + threadIdx.x;
  if (i == 0) {
    ((unsigned*)ws)[WS_MAX] = 0u;   // below any real orderedBits value
    ws[WS_SUM] = 0.f;
  }
  if (i < H) {
    const float r = 1.f / (1.f + expf(-(ws[WS_GI + i] + ws[WS_GH + i])));
    const float z = 1.f / (1.f + expf(-(ws[WS_GI + H + i] + ws[WS_GH + H + i])));
    const float n = tanhf(ws[WS_GI + 2 * H + i] + r * ws[WS_GH + 2 * H + i]);
    const float hn = (1.f - z) * n + z * hidden[i];
    ws[WS_HNEW + i] = hn;
    out[V + i] = hn;   // second output: new hidden state
  }
}

// K3: logits[v] = w_out[v,:] . h_new + b_out[v]; running max via atomicMax
__global__ __launch_bounds__(256) void logits_kernel(
    const float* __restrict__ w_out, const float* __restrict__ b_out,
    float* __restrict__ ws) {
  __shared__ float smax[4];
  const int wave = threadIdx.x >> 6;
  const int lane = threadIdx.x & 63;
  const int row = blockIdx.x * 4 + wave;
  float logit = -INFINITY;
  if (row < V) {
    const float4* w4 = (const float4*)(w_out + (size_t)row * H);
    const float4* h4 = (const float4*)(ws + WS_HNEW);
    float s = 0.f;
    #pragma unroll
    for (int k = 0; k < 8; ++k) {
      const int idx = k * 64 + lane;
      float4 a = w4[idx];
      float4 b = h4[idx];
      s += a.x * b.x + a.y * b.y + a.z * b.z + a.w * b.w;
    }
    s = waveReduceSum(s);
    if (lane == 0) {
      logit = s + b_out[row];
      ws[WS_LOGIT + row] = logit;
    }
  }
  if (lane == 0) smax[wave] = logit;
  __syncthreads();
  if (threadIdx.x == 0) {
    const float m = fmaxf(fmaxf(smax[0], smax[1]), fmaxf(smax[2], smax[3]));
    atomicMax((unsigned*)ws + WS_MAX, orderedBits(m));
  }
}

// K4: sum exp(logit - m) via block partials + atomicAdd
__global__ __launch_bounds__(256) void sumexp_kernel(float* __restrict__ ws) {
  const float m = orderedToFloat(((const unsigned*)ws)[WS_MAX]);
  float s = 0.f;
  for (int i = blockIdx.x * blockDim.x + threadIdx.x; i < V;
       i += gridDim.x * blockDim.x)
    s += expf(ws[WS_LOGIT + i] - m);
  s = waveReduceSum(s);
  __shared__ float sp[4];
  const int wave = threadIdx.x >> 6;
  const int lane = threadIdx.x & 63;
  if (lane == 0) sp[wave] = s;
  __syncthreads();
  if (threadIdx.x == 0)
    atomicAdd(ws + WS_SUM, sp[0] + sp[1] + sp[2] + sp[3]);
}

// K5: out[v] = logit[v] - (m + log(sum))
__global__ __launch_bounds__(256) void writeout_kernel(
    const float* __restrict__ ws, float* __restrict__ out) {
  const int i = blockIdx.x * blockDim.x + threadIdx.x;
  if (i < V) {
    const float m = orderedToFloat(((const unsigned*)ws)[WS_MAX]);
    const float lse = m + logf(ws[WS_SUM]);
    out[i] = ws[WS_LOGIT + i] - lse;
  }
}

extern "C" void kernel_launch(void* const* d_in, const int* in_sizes, int n_in,
                              void* d_out, int out_size, void* d_ws, size_t ws_size,
                              hipStream_t stream) {
  const int*   token  = (const int*)  d_in[0];
  const float* hidden = (const float*)d_in[1];
  const float* emb    = (const float*)d_in[2];
  const float* w_ih   = (const float*)d_in[3];
  const float* w_hh   = (const float*)d_in[4];
  const float* b_ih   = (const float*)d_in[5];
  const float* b_hh   = (const float*)d_in[6];
  const float* w_out  = (const float*)d_in[7];
  const float* b_out  = (const float*)d_in[8];
  float* out = (float*)d_out;
  float* ws  = (float*)d_ws;

  gates_kernel<<<G / 4, 256, 0, stream>>>(token, hidden, emb, w_ih, w_hh,
                                          b_ih, b_hh, ws);
  hnew_kernel<<<(H + 255) / 256, 256, 0, stream>>>(hidden, ws, out);
  logits_kernel<<<(V + 3) / 4, 256, 0, stream>>>(w_out, b_out, ws);
  sumexp_kernel<<<64, 256, 0, stream>>>(ws);
  writeout_kernel<<<(V + 255) / 256, 256, 0, stream>>>(ws, out);
}

// Round 2
// 752.990 us; speedup vs baseline: 1.0799x; 1.0799x over previous
//
#include <hip/hip_runtime.h>
#include <math.h>

#define H 2048
#define G 6144   // 3*H
#define V 50257

// ws layout (float indices):
// [0,     6144)  gi
// [6144, 12288)  gh
// [12288,14336)  h_new
// [14336]        max logit (ordered-uint bits)
// [14337]        sum exp(logit - m)
// [14344, 14344+V) logits
#define WS_GI    0
#define WS_GH    G
#define WS_HNEW  12288
#define WS_MAX   14336
#define WS_SUM   14337
#define WS_LOGIT 14344

__device__ __forceinline__ float waveReduceSum(float v) {
  #pragma unroll
  for (int off = 32; off > 0; off >>= 1) v += __shfl_down(v, off, 64);
  return v;
}
__device__ __forceinline__ float waveReduceMax(float v) {
  #pragma unroll
  for (int off = 32; off > 0; off >>= 1) v = fmaxf(v, __shfl_down(v, off, 64));
  return v;
}

__device__ __forceinline__ unsigned orderedBits(float f) {
  unsigned u = __float_as_uint(f);
  return (u & 0x80000000u) ? ~u : (u | 0x80000000u);
}
__device__ __forceinline__ float orderedToFloat(unsigned m) {
  unsigned u = (m & 0x80000000u) ? (m & 0x7fffffffu) : ~m;
  return __uint_as_float(u);
}

// K1: gi[r] = w_ih[r,:] . relu(emb[token]) + b_ih[r]
//     gh[r] = w_hh[r,:] . h + b_hh[r]
// one wave per row, 4 rows per block
__global__ __launch_bounds__(256) void gates_kernel(
    const int* __restrict__ token, const float* __restrict__ hidden,
    const float* __restrict__ emb, const float* __restrict__ w_ih,
    const float* __restrict__ w_hh, const float* __restrict__ b_ih,
    const float* __restrict__ b_hh, float* __restrict__ ws) {
  const int wave = threadIdx.x >> 6;
  const int lane = threadIdx.x & 63;
  const int row = blockIdx.x * 4 + wave;
  if (row >= G) return;
  const float4* x4 = (const float4*)(emb + (size_t)token[0] * H);
  const float4* h4 = (const float4*)hidden;
  const float4* wi = (const float4*)(w_ih + (size_t)row * H);
  const float4* wh = (const float4*)(w_hh + (size_t)row * H);
  float si = 0.f, sh = 0.f;
  #pragma unroll
  for (int k = 0; k < 8; ++k) {
    const int idx = k * 64 + lane;
    float4 a = wi[idx];
    float4 b = x4[idx];
    si += a.x * fmaxf(b.x, 0.f) + a.y * fmaxf(b.y, 0.f)
        + a.z * fmaxf(b.z, 0.f) + a.w * fmaxf(b.w, 0.f);
    float4 c = wh[idx];
    float4 d = h4[idx];
    sh += c.x * d.x + c.y * d.y + c.z * d.z + c.w * d.w;
  }
  si = waveReduceSum(si);
  sh = waveReduceSum(sh);
  if (lane == 0) {
    ws[WS_GI + row] = si + b_ih[row];
    ws[WS_GH + row] = sh + b_hh[row];
  }
}

// K2: pointwise GRU gate fusion -> h_new; also init softmax reduction cells
__global__ __launch_bounds__(256) void hnew_kernel(
    const float* __restrict__ hidden, float* __restrict__ ws,
    float* __restrict__ out) {
  const int i = blockIdx.x * blockDim.x + threadIdx.x;
  if (i == 0) {
    ((unsigned*)ws)[WS_MAX] = 0u;   // below any real orderedBits value
    ws[WS_SUM] = 0.f;
  }
  if (i < H) {
    const float r = 1.f / (1.f + expf(-(ws[WS_GI + i] + ws[WS_GH + i])));
    const float z = 1.f / (1.f + expf(-(ws[WS_GI + H + i] + ws[WS_GH + H + i])));
    const float n = tanhf(ws[WS_GI + 2 * H + i] + r * ws[WS_GH + 2 * H + i]);
    const float hn = (1.f - z) * n + z * hidden[i];
    ws[WS_HNEW + i] = hn;
    out[V + i] = hn;   // second output: new hidden state
  }
}

// K3: logits[v] = w_out[v,:] . h_new + b_out[v]  (no atomics — G12)
__global__ __launch_bounds__(256) void logits_kernel(
    const float* __restrict__ w_out, const float* __restrict__ b_out,
    float* __restrict__ ws) {
  const int wave = threadIdx.x >> 6;
  const int lane = threadIdx.x & 63;
  const int row = blockIdx.x * 4 + wave;
  if (row >= V) return;
  const float4* w4 = (const float4*)(w_out + (size_t)row * H);
  const float4* h4 = (const float4*)(ws + WS_HNEW);
  float s = 0.f;
  #pragma unroll
  for (int k = 0; k < 8; ++k) {
    const int idx = k * 64 + lane;
    float4 a = w4[idx];
    float4 b = h4[idx];
    s += a.x * b.x + a.y * b.y + a.z * b.z + a.w * b.w;
  }
  s = waveReduceSum(s);
  if (lane == 0) ws[WS_LOGIT + row] = s + b_out[row];
}

// K4: max over logits (L2-resident, 200 KB) — 128 atomics total
__global__ __launch_bounds__(256) void max_kernel(float* __restrict__ ws) {
  float m = -INFINITY;
  for (int i = blockIdx.x * blockDim.x + threadIdx.x; i < V;
       i += gridDim.x * blockDim.x)
    m = fmaxf(m, ws[WS_LOGIT + i]);
  m = waveReduceMax(m);
  __shared__ float sp[4];
  const int wave = threadIdx.x >> 6;
  const int lane = threadIdx.x & 63;
  if (lane == 0) sp[wave] = m;
  __syncthreads();
  if (threadIdx.x == 0) {
    const float bm = fmaxf(fmaxf(sp[0], sp[1]), fmaxf(sp[2], sp[3]));
    atomicMax((unsigned*)ws + WS_MAX, orderedBits(bm));
  }
}

// K5: sum exp(logit - m) via block partials + atomicAdd (64 atomics)
__global__ __launch_bounds__(256) void sumexp_kernel(float* __restrict__ ws) {
  const float m = orderedToFloat(((const unsigned*)ws)[WS_MAX]);
  float s = 0.f;
  for (int i = blockIdx.x * blockDim.x + threadIdx.x; i < V;
       i += gridDim.x * blockDim.x)
    s += expf(ws[WS_LOGIT + i] - m);
  s = waveReduceSum(s);
  __shared__ float sp[4];
  const int wave = threadIdx.x >> 6;
  const int lane = threadIdx.x & 63;
  if (lane == 0) sp[wave] = s;
  __syncthreads();
  if (threadIdx.x == 0)
    atomicAdd(ws + WS_SUM, sp[0] + sp[1] + sp[2] + sp[3]);
}

// K6: out[v] = logit[v] - (m + log(sum))
__global__ __launch_bounds__(256) void writeout_kernel(
    const float* __restrict__ ws, float* __restrict__ out) {
  const int i = blockIdx.x * blockDim.x + threadIdx.x;
  if (i < V) {
    const float m = orderedToFloat(((const unsigned*)ws)[WS_MAX]);
    const float lse = m + logf(ws[WS_SUM]);
    out[i] = ws[WS_LOGIT + i] - lse;
  }
}

extern "C" void kernel_launch(void* const* d_in, const int* in_sizes, int n_in,
                              void* d_out, int out_size, void* d_ws, size_t ws_size,
                              hipStream_t stream) {
  const int*   token  = (const int*)  d_in[0];
  const float* hidden = (const float*)d_in[1];
  const float* emb    = (const float*)d_in[2];
  const float* w_ih   = (const float*)d_in[3];
  const float* w_hh   = (const float*)d_in[4];
  const float* b_ih   = (const float*)d_in[5];
  const float* b_hh   = (const float*)d_in[6];
  const float* w_out  = (const float*)d_in[7];
  const float* b_out  = (const float*)d_in[8];
  float* out = (float*)d_out;
  float* ws  = (float*)d_ws;

  gates_kernel<<<G / 4, 256, 0, stream>>>(token, hidden, emb, w_ih, w_hh,
                                          b_ih, b_hh, ws);
  hnew_kernel<<<(H + 255) / 256, 256, 0, stream>>>(hidden, ws, out);
  logits_kernel<<<(V + 3) / 4, 256, 0, stream>>>(w_out, b_out, ws);
  max_kernel<<<128, 256, 0, stream>>>(ws);
  sumexp_kernel<<<64, 256, 0, stream>>>(ws);
  writeout_kernel<<<(V + 255) / 256, 256, 0, stream>>>(ws, out);
}

// Round 3
// 750.646 us; speedup vs baseline: 1.0833x; 1.0031x over previous
//
#include <hip/hip_runtime.h>
#include <math.h>

#define H 2048
#define G 6144   // 3*H
#define V 50257
#define NPART 128  // partial-reduction blocks for softmax

// ws layout (float indices):
// [0, 2048)           h_new
// [2048, 2048+V)      logits
// [53248, 53376)      per-block max partials
// [53376, 53504)      per-block sumexp partials
#define WS_HNEW  0
#define WS_LOGIT 2048
#define WS_PMAX  53248
#define WS_PSUM  53376

__device__ __forceinline__ float waveReduceSum(float v) {
  #pragma unroll
  for (int off = 32; off > 0; off >>= 1) v += __shfl_down(v, off, 64);
  return v;
}
__device__ __forceinline__ float waveReduceMax(float v) {
  #pragma unroll
  for (int off = 32; off > 0; off >>= 1) v = fmaxf(v, __shfl_down(v, off, 64));
  return v;
}
__device__ __forceinline__ float sigmoidf(float x) {
  return 1.f / (1.f + expf(-x));
}

// K1: fused GRU step. Wave owns h-index i; computes all six dot products
// (rows i, H+i, 2H+i of w_ih and w_hh) and the pointwise gate math.
__global__ __launch_bounds__(256) void gru_kernel(
    const int* __restrict__ token, const float* __restrict__ hidden,
    const float* __restrict__ emb, const float* __restrict__ w_ih,
    const float* __restrict__ w_hh, const float* __restrict__ b_ih,
    const float* __restrict__ b_hh, float* __restrict__ ws,
    float* __restrict__ out) {
  const int wave = threadIdx.x >> 6;
  const int lane = threadIdx.x & 63;
  const int i = blockIdx.x * 4 + wave;  // h-index in [0, H)
  const float4* x4 = (const float4*)(emb + (size_t)token[0] * H);
  const float4* h4 = (const float4*)hidden;
  const float4* wr_i = (const float4*)(w_ih + (size_t)i * H);
  const float4* wz_i = (const float4*)(w_ih + (size_t)(H + i) * H);
  const float4* wn_i = (const float4*)(w_ih + (size_t)(2 * H + i) * H);
  const float4* wr_h = (const float4*)(w_hh + (size_t)i * H);
  const float4* wz_h = (const float4*)(w_hh + (size_t)(H + i) * H);
  const float4* wn_h = (const float4*)(w_hh + (size_t)(2 * H + i) * H);
  float s_ir = 0.f, s_iz = 0.f, s_in = 0.f;
  float s_hr = 0.f, s_hz = 0.f, s_hn = 0.f;
  #pragma unroll
  for (int k = 0; k < 8; ++k) {
    const int idx = k * 64 + lane;
    float4 xv = x4[idx];
    xv.x = fmaxf(xv.x, 0.f); xv.y = fmaxf(xv.y, 0.f);
    xv.z = fmaxf(xv.z, 0.f); xv.w = fmaxf(xv.w, 0.f);
    float4 hv = h4[idx];
    float4 a;
    a = wr_i[idx]; s_ir += a.x*xv.x + a.y*xv.y + a.z*xv.z + a.w*xv.w;
    a = wz_i[idx]; s_iz += a.x*xv.x + a.y*xv.y + a.z*xv.z + a.w*xv.w;
    a = wn_i[idx]; s_in += a.x*xv.x + a.y*xv.y + a.z*xv.z + a.w*xv.w;
    a = wr_h[idx]; s_hr += a.x*hv.x + a.y*hv.y + a.z*hv.z + a.w*hv.w;
    a = wz_h[idx]; s_hz += a.x*hv.x + a.y*hv.y + a.z*hv.z + a.w*hv.w;
    a = wn_h[idx]; s_hn += a.x*hv.x + a.y*hv.y + a.z*hv.z + a.w*hv.w;
  }
  s_ir = waveReduceSum(s_ir);
  s_iz = waveReduceSum(s_iz);
  s_in = waveReduceSum(s_in);
  s_hr = waveReduceSum(s_hr);
  s_hz = waveReduceSum(s_hz);
  s_hn = waveReduceSum(s_hn);
  if (lane == 0) {
    const float r = sigmoidf(s_ir + b_ih[i] + s_hr + b_hh[i]);
    const float z = sigmoidf(s_iz + b_ih[H + i] + s_hz + b_hh[H + i]);
    const float n = tanhf(s_in + b_ih[2 * H + i] + r * (s_hn + b_hh[2 * H + i]));
    const float hn = (1.f - z) * n + z * hidden[i];
    ws[WS_HNEW + i] = hn;
    out[V + i] = hn;   // second output: new hidden state
  }
}

// K2: logits[v] = w_out[v,:] . h_new + b_out[v]
__global__ __launch_bounds__(256) void logits_kernel(
    const float* __restrict__ w_out, const float* __restrict__ b_out,
    float* __restrict__ ws) {
  const int wave = threadIdx.x >> 6;
  const int lane = threadIdx.x & 63;
  const int row = blockIdx.x * 4 + wave;
  if (row >= V) return;
  const float4* w4 = (const float4*)(w_out + (size_t)row * H);
  const float4* h4 = (const float4*)(ws + WS_HNEW);
  float s = 0.f;
  #pragma unroll
  for (int k = 0; k < 8; ++k) {
    const int idx = k * 64 + lane;
    float4 a = w4[idx];
    float4 b = h4[idx];
    s += a.x * b.x + a.y * b.y + a.z * b.z + a.w * b.w;
  }
  s = waveReduceSum(s);
  if (lane == 0) ws[WS_LOGIT + row] = s + b_out[row];
}

// K3: per-block (max, sumexp) partials over logits (L2-resident). No atomics.
__global__ __launch_bounds__(256) void partial_kernel(float* __restrict__ ws) {
  __shared__ float sred[4];
  __shared__ float sbmax;
  const int wave = threadIdx.x >> 6;
  const int lane = threadIdx.x & 63;
  float m = -INFINITY;
  for (int i = blockIdx.x * 256 + threadIdx.x; i < V; i += NPART * 256)
    m = fmaxf(m, ws[WS_LOGIT + i]);
  m = waveReduceMax(m);
  if (lane == 0) sred[wave] = m;
  __syncthreads();
  if (threadIdx.x == 0)
    sbmax = fmaxf(fmaxf(sred[0], sred[1]), fmaxf(sred[2], sred[3]));
  __syncthreads();
  const float M = sbmax;
  float s = 0.f;
  for (int i = blockIdx.x * 256 + threadIdx.x; i < V; i += NPART * 256)
    s += expf(ws[WS_LOGIT + i] - M);
  s = waveReduceSum(s);
  __syncthreads();
  if (lane == 0) sred[wave] = s;
  __syncthreads();
  if (threadIdx.x == 0) {
    ws[WS_PMAX + blockIdx.x] = M;
    ws[WS_PSUM + blockIdx.x] = sred[0] + sred[1] + sred[2] + sred[3];
  }
}

// K4: combine 128 partial pairs (redundantly per block) + write out.
__global__ __launch_bounds__(256) void writeout_kernel(
    const float* __restrict__ ws, float* __restrict__ out) {
  __shared__ float pm[NPART], psv[NPART];
  if (threadIdx.x < NPART) {
    pm[threadIdx.x]  = ws[WS_PMAX + threadIdx.x];
    psv[threadIdx.x] = ws[WS_PSUM + threadIdx.x];
  }
  __syncthreads();
  float M = -INFINITY;
  #pragma unroll
  for (int j = 0; j < NPART; ++j) M = fmaxf(M, pm[j]);
  float S = 0.f;
  #pragma unroll
  for (int j = 0; j < NPART; ++j) S += psv[j] * expf(pm[j] - M);
  const float lse = M + logf(S);
  const int i = blockIdx.x * 256 + threadIdx.x;
  if (i < V) out[i] = ws[WS_LOGIT + i] - lse;
}

extern "C" void kernel_launch(void* const* d_in, const int* in_sizes, int n_in,
                              void* d_out, int out_size, void* d_ws, size_t ws_size,
                              hipStream_t stream) {
  const int*   token  = (const int*)  d_in[0];
  const float* hidden = (const float*)d_in[1];
  const float* emb    = (const float*)d_in[2];
  const float* w_ih   = (const float*)d_in[3];
  const float* w_hh   = (const float*)d_in[4];
  const float* b_ih   = (const float*)d_in[5];
  const float* b_hh   = (const float*)d_in[6];
  const float* w_out  = (const float*)d_in[7];
  const float* b_out  = (const float*)d_in[8];
  float* out = (float*)d_out;
  float* ws  = (float*)d_ws;

  gru_kernel<<<H / 4, 256, 0, stream>>>(token, hidden, emb, w_ih, w_hh,
                                        b_ih, b_hh, ws, out);
  logits_kernel<<<(V + 3) / 4, 256, 0, stream>>>(w_out, b_out, ws);
  partial_kernel<<<NPART, 256, 0, stream>>>(ws);
  writeout_kernel<<<(V + 255) / 256, 256, 0, stream>>>(ws, out);
}